// Round 1
// baseline (529.156 us; speedup 1.0000x reference)
//
#include <hip/hip_runtime.h>

// Problem constants (fixed by reference setup_inputs)
constexpr int B = 16;
constexpr int C = 256;
constexpr int T = 16000;
constexpr int Q = T / 4;          // float4 elements per (b,c) row = 4000
constexpr float EPS = 1e-8f;
constexpr int CPB = 8;            // channels per block in apply kernel

// ---------------------------------------------------------------------------
// Phase 1: per-(b,t) channel reduction -> step_sum[B,T], step_pow[B,T]
// Each thread owns 4 consecutive t (one float4), loops over all C channels.
// Wave access per iteration: 64 lanes x 16B = 1024B contiguous (coalesced).
// ---------------------------------------------------------------------------
__global__ __launch_bounds__(256) void step_sums_kernel(
    const float* __restrict__ x,
    float* __restrict__ ssum,
    float* __restrict__ spow) {
  const int b  = blockIdx.y;
  const int t4 = blockIdx.x * blockDim.x + threadIdx.x;
  if (t4 >= Q) return;

  const float4* xb = reinterpret_cast<const float4*>(x + (size_t)b * C * T);
  float4 s = make_float4(0.f, 0.f, 0.f, 0.f);
  float4 p = make_float4(0.f, 0.f, 0.f, 0.f);

#pragma unroll 8
  for (int c = 0; c < C; ++c) {
    float4 v = xb[(size_t)c * Q + t4];
    s.x += v.x; s.y += v.y; s.z += v.z; s.w += v.w;
    p.x = fmaf(v.x, v.x, p.x);
    p.y = fmaf(v.y, v.y, p.y);
    p.z = fmaf(v.z, v.z, p.z);
    p.w = fmaf(v.w, v.w, p.w);
  }
  reinterpret_cast<float4*>(ssum + (size_t)b * T)[t4] = s;
  reinterpret_cast<float4*>(spow + (size_t)b * T)[t4] = p;
}

// ---------------------------------------------------------------------------
// Phase 2: per-batch inclusive scan over T of (step_sum, step_pow), then
// convert to mean / inv_std in place. One block (256 thr) per batch.
// Chunked scan: wave shfl_up scan + LDS wave totals; inter-chunk carry kept
// in double to avoid fp32 cumsum drift over 16000 additions of ~256-sized
// values (max cum_pow_sum ~4.1e6).
// ---------------------------------------------------------------------------
__global__ __launch_bounds__(256) void scan_kernel(
    float* __restrict__ ssum,   // in: step_sum  / out: cum_mean
    float* __restrict__ spow) { // in: step_pow  / out: inv_std
  const int b = blockIdx.x;
  float* s = ssum + (size_t)b * T;
  float* p = spow + (size_t)b * T;

  __shared__ float ws_s[4];
  __shared__ float ws_p[4];

  const int tid  = threadIdx.x;
  const int lane = tid & 63;
  const int wid  = tid >> 6;

  double carry_s = 0.0;
  double carry_p = 0.0;

  for (int base = 0; base < T; base += 256) {
    const int i = base + tid;
    float cs = (i < T) ? s[i] : 0.f;
    float cp = (i < T) ? p[i] : 0.f;

    // inclusive wave scan (64 lanes)
#pragma unroll
    for (int off = 1; off < 64; off <<= 1) {
      float ns = __shfl_up(cs, off);
      float np = __shfl_up(cp, off);
      if (lane >= off) { cs += ns; cp += np; }
    }
    if (lane == 63) { ws_s[wid] = cs; ws_p[wid] = cp; }
    __syncthreads();

    float add_s = 0.f, add_p = 0.f;
#pragma unroll
    for (int w = 0; w < 4; ++w) {
      if (w < wid) { add_s += ws_s[w]; add_p += ws_p[w]; }
    }
    const float tot_s = ws_s[0] + ws_s[1] + ws_s[2] + ws_s[3];
    const float tot_p = ws_p[0] + ws_p[1] + ws_p[2] + ws_p[3];

    const double cum_s = carry_s + (double)(cs + add_s);
    const double cum_p = carry_p + (double)(cp + add_p);

    if (i < T) {
      const float cnt  = (float)(i + 1) * (float)C;   // exact in fp32 (<=4.096e6)
      const float mean = (float)cum_s / cnt;
      const float var  = (float)cum_p / cnt - mean * mean;
      const float istd = rsqrtf(var + EPS);
      s[i] = mean;
      p[i] = istd;
    }

    carry_s += (double)tot_s;
    carry_p += (double)tot_p;
    __syncthreads();  // protect ws_* before next chunk overwrites
  }
}

// ---------------------------------------------------------------------------
// Phase 3: elementwise apply. Each thread loads its mean4/istd4 once and
// reuses them across CPB channels (8x fewer [B,T] re-reads; rest L2-cached).
// ---------------------------------------------------------------------------
__global__ __launch_bounds__(256) void apply_kernel(
    const float* __restrict__ x,
    const float* __restrict__ mean,
    const float* __restrict__ istd,
    const float* __restrict__ gain,
    const float* __restrict__ bias,
    float* __restrict__ out) {
  const int b  = blockIdx.z;
  const int c0 = blockIdx.y * CPB;
  const int t4 = blockIdx.x * blockDim.x + threadIdx.x;
  if (t4 >= Q) return;

  const float4 m  = reinterpret_cast<const float4*>(mean + (size_t)b * T)[t4];
  const float4 is = reinterpret_cast<const float4*>(istd + (size_t)b * T)[t4];

  const float4* xb = reinterpret_cast<const float4*>(x   + ((size_t)b * C + c0) * T);
  float4*       ob = reinterpret_cast<float4*>      (out + ((size_t)b * C + c0) * T);

#pragma unroll
  for (int i = 0; i < CPB; ++i) {
    const float g  = gain[c0 + i];
    const float bi = bias[c0 + i];
    float4 v = xb[(size_t)i * Q + t4];
    float4 o;
    o.x = (v.x - m.x) * is.x * g + bi;
    o.y = (v.y - m.y) * is.y * g + bi;
    o.z = (v.z - m.z) * is.z * g + bi;
    o.w = (v.w - m.w) * is.w * g + bi;
    ob[(size_t)i * Q + t4] = o;
  }
}

extern "C" void kernel_launch(void* const* d_in, const int* in_sizes, int n_in,
                              void* d_out, int out_size, void* d_ws, size_t ws_size,
                              hipStream_t stream) {
  const float* x    = (const float*)d_in[0];
  const float* gain = (const float*)d_in[1];
  const float* bias = (const float*)d_in[2];
  float* out = (float*)d_out;

  // Workspace layout: step_sum[B*T] | step_pow[B*T]  (2.05 MB total)
  float* ssum = (float*)d_ws;
  float* spow = ssum + (size_t)B * T;

  dim3 g1((Q + 255) / 256, B);
  step_sums_kernel<<<g1, 256, 0, stream>>>(x, ssum, spow);

  scan_kernel<<<B, 256, 0, stream>>>(ssum, spow);

  dim3 g3((Q + 255) / 256, C / CPB, B);
  apply_kernel<<<g3, 256, 0, stream>>>(x, ssum, spow, gain, bias, out);
}

// Round 2
// 477.982 us; speedup vs baseline: 1.1071x; 1.1071x over previous
//
#include <hip/hip_runtime.h>

// Problem constants (fixed by reference setup_inputs)
constexpr int B = 16;
constexpr int C = 256;
constexpr int T = 16000;
constexpr int Q = T / 4;          // float4 elements per (b) row = 4000
constexpr float EPS = 1e-8f;
constexpr int CG  = 4;            // channel groups in phase 1 (occupancy)
constexpr int CPG = C / CG;       // 64 channels per group
constexpr int CPB = 8;            // channels per block in apply kernel
constexpr int RUN = 16;           // float4s per thread in scan kernel (250 active thr)

typedef float f4 __attribute__((ext_vector_type(4)));

// ---------------------------------------------------------------------------
// Phase 1: partial channel reduction. Block (t-chunk, group g, b) sums 64
// channels -> ssum_part[g][b][T], spow_part[g][b][T]. 1024 blocks (4/CU).
// x loads are nontemporal (no reuse before apply; 262MB >> caches anyway).
// ---------------------------------------------------------------------------
__global__ __launch_bounds__(256) void step_sums_kernel(
    const float* __restrict__ x,
    float* __restrict__ ssum_part,
    float* __restrict__ spow_part) {
  const int b  = blockIdx.z;
  const int g  = blockIdx.y;
  const int t4 = blockIdx.x * blockDim.x + threadIdx.x;
  if (t4 >= Q) return;

  const f4* xb = reinterpret_cast<const f4*>(x + ((size_t)b * C + (size_t)g * CPG) * T);
  f4 s = {0.f, 0.f, 0.f, 0.f};
  f4 p = {0.f, 0.f, 0.f, 0.f};

#pragma unroll 8
  for (int c = 0; c < CPG; ++c) {
    f4 v = __builtin_nontemporal_load(&xb[(size_t)c * Q + t4]);
    s += v;
    p += v * v;
  }
  reinterpret_cast<f4*>(ssum_part + ((size_t)g * B + b) * T)[t4] = s;
  reinterpret_cast<f4*>(spow_part + ((size_t)g * B + b) * T)[t4] = p;
}

// ---------------------------------------------------------------------------
// Phase 2: one block per b. Thread j owns float4s [j*16, j*16+16) (contiguous
// 64 scalars in registers). Sum the 4 partial groups, serial-scan the run,
// block-scan run totals in double (fp32 cumsum over 16000 x ~256-sized values
// drifts; double carry kills it), then emit mean / inv_std.
// ---------------------------------------------------------------------------
__global__ __launch_bounds__(256) void scan_kernel(
    const float* __restrict__ ssum_part,
    const float* __restrict__ spow_part,
    float* __restrict__ mean_out,
    float* __restrict__ istd_out) {
  const int b   = blockIdx.x;
  const int j   = threadIdx.x;
  const int lane = j & 63;
  const int wid  = j >> 6;
  const bool active = (j * RUN) < Q;   // j < 250

  f4 S[RUN], P[RUN];
#pragma unroll
  for (int k = 0; k < RUN; ++k) { S[k] = (f4){0,0,0,0}; P[k] = (f4){0,0,0,0}; }

  if (active) {
#pragma unroll
    for (int g = 0; g < CG; ++g) {
      const f4* sp = reinterpret_cast<const f4*>(ssum_part + ((size_t)g * B + b) * T);
      const f4* pp = reinterpret_cast<const f4*>(spow_part + ((size_t)g * B + b) * T);
#pragma unroll
      for (int k = 0; k < RUN; ++k) {
        S[k] += sp[j * RUN + k];
        P[k] += pp[j * RUN + k];
      }
    }
  }

  // serial inclusive scan over this thread's 64 scalars (fp32: run is short)
  float rs = 0.f, rp = 0.f;
#pragma unroll
  for (int k = 0; k < RUN; ++k) {
#pragma unroll
    for (int c = 0; c < 4; ++c) {
      rs += S[k][c]; S[k][c] = rs;
      rp += P[k][c]; P[k][c] = rp;
    }
  }

  // block exclusive scan of run totals in double
  const double ts = (double)rs, tp = (double)rp;
  double cs = ts, cp = tp;
#pragma unroll
  for (int off = 1; off < 64; off <<= 1) {
    double ns = __shfl_up(cs, off);
    double np = __shfl_up(cp, off);
    if (lane >= off) { cs += ns; cp += np; }
  }
  __shared__ double wss[4], wsp[4];
  if (lane == 63) { wss[wid] = cs; wsp[wid] = cp; }
  __syncthreads();

  double pre_s = cs - ts;   // exclusive within wave
  double pre_p = cp - tp;
#pragma unroll
  for (int w = 0; w < 4; ++w) {
    if (w < wid) { pre_s += wss[w]; pre_p += wsp[w]; }
  }

  if (active) {
    f4* mo = reinterpret_cast<f4*>(mean_out + (size_t)b * T);
    f4* io = reinterpret_cast<f4*>(istd_out + (size_t)b * T);
#pragma unroll
    for (int k = 0; k < RUN; ++k) {
      f4 m, iv;
#pragma unroll
      for (int c = 0; c < 4; ++c) {
        const int i = (j * RUN + k) * 4 + c;          // t index
        const float cnt = (float)(i + 1) * (float)C;  // exact in fp32 (<=4.096e6)
        const float cum_s = (float)(pre_s + (double)S[k][c]);
        const float cum_p = (float)(pre_p + (double)P[k][c]);
        const float mean  = cum_s / cnt;
        const float var   = cum_p / cnt - mean * mean;
        m[c]  = mean;
        iv[c] = rsqrtf(var + EPS);
      }
      mo[j * RUN + k] = m;
      io[j * RUN + k] = iv;
    }
  }
}

// ---------------------------------------------------------------------------
// Phase 3: elementwise apply. Thread loads mean4/istd4 once (L2/L3-cached,
// reused across CPB channels); x loads and out stores are nontemporal
// (zero reuse -> keep them out of the cache fill path).
// ---------------------------------------------------------------------------
__global__ __launch_bounds__(256) void apply_kernel(
    const float* __restrict__ x,
    const float* __restrict__ mean,
    const float* __restrict__ istd,
    const float* __restrict__ gain,
    const float* __restrict__ bias,
    float* __restrict__ out) {
  const int b  = blockIdx.z;
  const int c0 = blockIdx.y * CPB;
  const int t4 = blockIdx.x * blockDim.x + threadIdx.x;
  if (t4 >= Q) return;

  const f4 m  = reinterpret_cast<const f4*>(mean + (size_t)b * T)[t4];
  const f4 is = reinterpret_cast<const f4*>(istd + (size_t)b * T)[t4];

  const f4* xb = reinterpret_cast<const f4*>(x   + ((size_t)b * C + c0) * T);
  f4*       ob = reinterpret_cast<f4*>      (out + ((size_t)b * C + c0) * T);

#pragma unroll
  for (int i = 0; i < CPB; ++i) {
    const float g  = gain[c0 + i];
    const float bi = bias[c0 + i];
    f4 v = __builtin_nontemporal_load(&xb[(size_t)i * Q + t4]);
    f4 o = (v - m) * is * g + bi;
    __builtin_nontemporal_store(o, &ob[(size_t)i * Q + t4]);
  }
}

extern "C" void kernel_launch(void* const* d_in, const int* in_sizes, int n_in,
                              void* d_out, int out_size, void* d_ws, size_t ws_size,
                              hipStream_t stream) {
  const float* x    = (const float*)d_in[0];
  const float* gain = (const float*)d_in[1];
  const float* bias = (const float*)d_in[2];
  float* out = (float*)d_out;

  // ws layout: ssum_part[CG][B][T] | spow_part[CG][B][T] | mean[B][T] | istd[B][T]
  float* ssum_part = (float*)d_ws;
  float* spow_part = ssum_part + (size_t)CG * B * T;
  float* mean      = spow_part + (size_t)CG * B * T;
  float* istd      = mean      + (size_t)B * T;

  dim3 g1((Q + 255) / 256, CG, B);
  step_sums_kernel<<<g1, 256, 0, stream>>>(x, ssum_part, spow_part);

  scan_kernel<<<B, 256, 0, stream>>>(ssum_part, spow_part, mean, istd);

  dim3 g3((Q + 255) / 256, C / CPB, B);
  apply_kernel<<<g3, 256, 0, stream>>>(x, mean, istd, gain, bias, out);
}